// Round 11
// baseline (29.001 us; speedup 1.0000x reference)
//
#include <hip/hip_runtime.h>

// ThetaGammaCLEVRN — all-MFMA formulation (R11 = R10 + builtin-name fix).
// Math reduction (phase network dead; theta amps == 1):
//   sf[16] = sum_o scene[e,o,:]
//   x[g]   = sf@(0.1*Ws) + bs           -> mfma_f32_16x16x16f16 (4 tiles)
//   ga[g]  = F20(sigmoid(x[g]))         -> 512-entry LUT
//   h      = relu(W @ act)              -> mfma_f32_16x16x32_f16 (16)
//   out    = log_softmax(h @ W2 + b2)
// k-PERMUTATION TRICK: H = W@act is invariant under k-reordering applied to
// BOTH W's columns (prep) and act's slots (runtime). We choose the order so
// the x-MFMA D-layout lands exactly in this lane's H B-frag slots:
//   slot k = 32c+8kb+i  ->  g(k) = (2c+(i>>2))*16 + 4kb + (i&3)   [bijective]
// -> zero cross-lane ops between x-MFMA and H-MFMA.
// W is read from GLOBAL (L2-resident) per-lane instead of LDS: LDS 34.8->18.2
// KB, 5 blocks/CU with __launch_bounds__(256,5).

typedef __fp16 h2_t  __attribute__((ext_vector_type(2)));
typedef __fp16 f16x4 __attribute__((ext_vector_type(4)));
typedef __fp16 f16x8 __attribute__((ext_vector_type(8)));
typedef float  f32x4 __attribute__((ext_vector_type(4)));
typedef unsigned u32x4 __attribute__((ext_vector_type(4)));

union H2U { unsigned u; h2_t h; };
union F4  { unsigned u[2]; f16x4 h; };
union F8  { u32x4 u; f16x8 h; };

__device__ __forceinline__ unsigned pk(float a, float b) {
    H2U v; v.h = __builtin_amdgcn_cvt_pkrtz(a, b);
    return v.u;
}
__device__ __forceinline__ float F20(float g) {
    #pragma unroll
    for (int n = 0; n < 20; ++n) {
        float g2 = g * g;
        g = fmaf(0.01f, g * (1.0f - g2), g);
    }
    return g;
}

// ws global layout (u32/f32 words):
//   0    : Wh   [64][64] fp16 pairs, row j, pair p: k-slots (2p,2p+1), with
//          gamma part (p<32) PERMUTED: g(k) as above; query part identity.
//   4096 : ws2T [8][64]  fp16 pairs (0.1*Ws[2dp][g], 0.1*Ws[2dp+1][g])
//   4608 : LUT  [512]x2  (F(x_i), F(x_{i+1})-F(x_i)), x_i = i/64 - 4
//   5632 : bs   [64] f32
//   5696 : w2   [128] f32 (W2 row-major)
//   5824 : b2   [2] f32 ; pad zeros to 5888
#define NWP 5888

__global__ void prep_kernel(const float* __restrict__ Ws,
                            const float* __restrict__ bs,
                            const float* __restrict__ Wq,
                            const float* __restrict__ bq,
                            const float* __restrict__ W1,
                            const float* __restrict__ b1,
                            const float* __restrict__ W2,
                            const float* __restrict__ b2,
                            float* __restrict__ ws) {
    unsigned* wsu = (unsigned*)ws;
    int gid = blockIdx.x * 256 + threadIdx.x;
    if (gid < 4096) {                         // Wh pairs
        int j = gid >> 6, p = gid & 63;
        float va = 0.f, vb = 0.f;
        if (p < 32) {                         // gamma, k-permuted
            int c = p >> 4, kb = (p >> 2) & 3, i0 = (2 * p) & 7;
            int g0 = ((c << 1) + (i0 >> 2)) * 16 + (kb << 2) + (i0 & 3);
            va = W1[(16 + g0) * 64 + j];
            vb = W1[(17 + g0) * 64 + j];
        } else if (p < 62) {                  // Weff dims d0,d0+1 (identity)
            int d0 = 2 * p - 64;
            float s0 = 0.f, s1 = 0.f;
            #pragma unroll 16
            for (int c = 0; c < 64; ++c) {
                float w = W1[(80 + c) * 64 + j];
                s0 = fmaf(Wq[d0 * 64 + c], w, s0);
                s1 = fmaf(Wq[(d0 + 1) * 64 + c], w, s1);
            }
            va = s0; vb = s1;
        } else if (p == 62) {                 // k=124: beff ; k=125: 0
            float acc = b1[j];
            #pragma unroll
            for (int r = 0; r < 16; ++r) acc += W1[r * 64 + j];
            #pragma unroll 16
            for (int c = 0; c < 64; ++c)
                acc = fmaf(bq[c], W1[(80 + c) * 64 + j], acc);
            va = acc; vb = 0.f;
        }
        wsu[gid] = pk(va, vb);
    } else if (gid < 4608) {                  // ws2T
        int w = gid - 4096, dp = w >> 6, g = w & 63;
        wsu[gid] = pk(0.1f * Ws[(2 * dp) * 64 + g],
                      0.1f * Ws[(2 * dp + 1) * 64 + g]);
    } else if (gid < 5632) {                  // LUT
        int li = gid - 4608, i = li >> 1;
        float x0 = (float)i * 0.015625f - 4.0f;
        float F0 = F20(1.0f / (1.0f + expf(-x0)));
        if (li & 1) {
            float F1 = F20(1.0f / (1.0f + expf(-(x0 + 0.015625f))));
            ws[gid] = F1 - F0;
        } else {
            ws[gid] = F0;
        }
    } else if (gid < 5696) {                  // bs
        ws[gid] = bs[gid - 5632];
    } else if (gid < 5824) {                  // W2 flat copy
        ws[gid] = W2[gid - 5696];
    } else if (gid < NWP) {
        ws[gid] = (gid == 5824) ? b2[0] : (gid == 5825) ? b2[1] : 0.f;
    }
}

// LDS word offsets (small consts only; W stays in global/L2)
#define CWS  0             // ws2T [8][64]
#define CLUT 512           // LUT float2[512]
#define CBS  1536          // bs [64]
#define CW2  1600          // W2 [128]
#define ACTo 1728          // sfT[8][64] at +0, qT[32][72] at +512
#define QP   72
#define LDSW (ACTo + 512 + 32 * QP)   // 4544 words = 18.2 KB

__global__ __launch_bounds__(256, 5) void fused_kernel(
    const float* __restrict__ scene,   // (B,10,16)
    const float* __restrict__ query,   // (B,60)
    const float* __restrict__ wsbuf,   // NWP words
    float* __restrict__ out)           // (B,2)
{
    __shared__ __align__(16) unsigned lds[LDSW];
    const int t    = threadIdx.x;
    const int lane = t & 63;
    const int wv   = __builtin_amdgcn_readfirstlane(t) >> 6;
    const int eb   = blockIdx.x << 6;      // 64 elements per block
    const unsigned* wsu = (const unsigned*)wsbuf;
    const float* ldsf = (const float*)lds;

    // ---- 1) async const staging: 7 chunks x 1 KB (global 4096..5887) ----
    #pragma unroll
    for (int i = 0; i < 2; ++i) {
        const int c = wv + (i << 2);
        if (c < 7)
            __builtin_amdgcn_global_load_lds(
                (const __attribute__((address_space(1))) unsigned*)
                    (wsu + 4096 + (c << 8) + (lane << 2)),
                (__attribute__((address_space(3))) unsigned*)&lds[c << 8],
                16, 0, 0);
    }

    const int sel = t >> 2, q4 = t & 3;
    // ---- 2) scene: object-sum -> transposed fp16 pairs sfT[8][64] ----
    {
        const float4* sp = (const float4*)scene + (size_t)(eb + sel) * 40 + q4;
        float4 a = sp[0];
        #pragma unroll
        for (int o = 1; o < 10; ++o) {
            float4 v = sp[4 * o];
            a.x += v.x; a.y += v.y; a.z += v.z; a.w += v.w;
        }
        lds[ACTo + ((q4 << 1) + 0) * 64 + sel] = pk(a.x, a.y);
        lds[ACTo + ((q4 << 1) + 1) * 64 + sel] = pk(a.z, a.w);
    }
    // ---- 3) query -> transposed fp16 pairs qT[32][72] ----
    #pragma unroll
    for (int i = 0; i < 4; ++i) {
        const int idx = t + (i << 8);
        if (idx < 960) {
            const int qel = idx / 15, kq = idx - qel * 15;
            float4 qv = ((const float4*)query)[(size_t)(eb + qel) * 15 + kq];
            lds[ACTo + 512 + (2 * kq + 0) * QP + qel] = pk(qv.x, qv.y);
            lds[ACTo + 512 + (2 * kq + 1) * QP + qel] = pk(qv.z, qv.w);
        }
    }
    // ---- 4) pad rows: k=124 const-1 (beff), k=125..127 zero ----
    if (t < 64)       lds[ACTo + 512 + 30 * QP + t]        = pk(1.0f, 0.0f);
    else if (t < 128) lds[ACTo + 512 + 31 * QP + (t - 64)] = 0u;

    __syncthreads();   // consts + activations ready (drains gload_lds)

    // ============ compute: wave owns 16 elements (one MFMA N-tile) ========
    const int kb  = lane >> 4;
    const int q   = lane & 15;
    const int elb = ((t >> 6) << 4) | q;

    // ---- x-MFMAs: x[g][el] = bs[g] + sf @ (0.1*Ws), 4 tiles of 16 g ----
    F4 bsf;
    bsf.u[0] = lds[ACTo + (2 * kb + 0) * 64 + elb];
    bsf.u[1] = lds[ACTo + (2 * kb + 1) * 64 + elb];
    f32x4 xs[4];
    #pragma unroll
    for (int tt = 0; tt < 4; ++tt) {
        F4 aW;
        aW.u[0] = lds[CWS + (2 * kb + 0) * 64 + tt * 16 + q];
        aW.u[1] = lds[CWS + (2 * kb + 1) * 64 + tt * 16 + q];
        f32x4 cinit = *(const f32x4*)&ldsf[CBS + tt * 16 + (kb << 2)];
        xs[tt] = __builtin_amdgcn_mfma_f32_16x16x16f16(aW.h, bsf.h, cinit, 0, 0, 0);
    }

    // ---- LUT (sigmoid + 20-step Euler fused) + pack B-frags ----
    auto GA = [&](float x) -> float {
        float u = fminf(fmaxf(fmaf(x, 64.0f, 256.0f), 0.0f), 511.0f);
        int   i0 = (int)u;
        float2 e = *(const float2*)&ldsf[CLUT + (i0 << 1)];
        return fmaf(u - (float)i0, e.y, e.x);
    };
    F8 bfrag[4];
    #pragma unroll
    for (int c = 0; c < 2; ++c) {
        F8 f;
        f.u[0] = pk(GA(xs[2 * c][0]),     GA(xs[2 * c][1]));
        f.u[1] = pk(GA(xs[2 * c][2]),     GA(xs[2 * c][3]));
        f.u[2] = pk(GA(xs[2 * c + 1][0]), GA(xs[2 * c + 1][1]));
        f.u[3] = pk(GA(xs[2 * c + 1][2]), GA(xs[2 * c + 1][3]));
        bfrag[c] = f;
    }
    // ---- query B-frags c=2,3 (includes const-1 beff column) ----
    #pragma unroll
    for (int c2 = 0; c2 < 2; ++c2) {
        F8 f;
        #pragma unroll
        for (int r = 0; r < 4; ++r)
            f.u[r] = lds[ACTo + 512 + ((kb << 2) + r + (c2 << 4)) * QP + elb];
        bfrag[2 + c2] = f;
    }

    // ---- H-MFMA: 4 j-tiles x 4 k-chunks; W A-frags from GLOBAL (L2) ----
    const u32x4* WgG = (const u32x4*)wsu;
    float l0 = 0.f, l1 = 0.f;
    #pragma unroll
    for (int jt = 0; jt < 4; ++jt) {
        f32x4 acc = {0.f, 0.f, 0.f, 0.f};
        const int j = (jt << 4) | q;
        #pragma unroll
        for (int c = 0; c < 4; ++c) {
            F8 a;
            a.u = WgG[(j << 4) + (c << 2) + kb];
            acc = __builtin_amdgcn_mfma_f32_16x16x32_f16(a.h, bfrag[c].h, acc, 0, 0, 0);
        }
        #pragma unroll
        for (int r = 0; r < 4; ++r) {
            const int jr = (jt << 4) + (kb << 2) + r;
            float hv = fmaxf(acc[r], 0.f);
            float2 wv2 = *(const float2*)&ldsf[CW2 + (jr << 1)];
            l0 = fmaf(hv, wv2.x, l0);
            l1 = fmaf(hv, wv2.y, l1);
        }
    }
    // ---- reduce over k-groups, log_softmax, store ----
    l0 += __shfl_xor(l0, 16); l0 += __shfl_xor(l0, 32);
    l1 += __shfl_xor(l1, 16); l1 += __shfl_xor(l1, 32);
    l0 += wsbuf[5824]; l1 += wsbuf[5825];
    if (lane < 16) {
        const float mx = fmaxf(l0, l1);
        const float lz = mx + __logf(__expf(l0 - mx) + __expf(l1 - mx));
        float2 o = { l0 - lz, l1 - lz };
        ((float2*)out)[eb + elb] = o;
    }
}

extern "C" void kernel_launch(void* const* d_in, const int* in_sizes, int n_in,
                              void* d_out, int out_size, void* d_ws, size_t ws_size,
                              hipStream_t stream) {
    const float* scene = (const float*)d_in[0];
    const float* query = (const float*)d_in[1];
    // d_in[2..5] = theta/gamma phase & freq: provably unused by the output
    const float* Ws = (const float*)d_in[6];
    const float* bs = (const float*)d_in[7];
    const float* Wq = (const float*)d_in[8];
    const float* bq = (const float*)d_in[9];
    const float* W1 = (const float*)d_in[10];
    const float* b1 = (const float*)d_in[11];
    const float* W2 = (const float*)d_in[12];
    const float* b2 = (const float*)d_in[13];
    float* out = (float*)d_out;
    float* ws  = (float*)d_ws;   // needs NWP*4 = 23.6 KB

    const int B = in_sizes[0] / 160;   // 65536
    prep_kernel<<<23, 256, 0, stream>>>(Ws, bs, Wq, bq, W1, b1, W2, b2, ws);
    fused_kernel<<<B / 64, 256, 0, stream>>>(scene, query, ws, out);
}

// Round 12
// 23.335 us; speedup vs baseline: 1.2428x; 1.2428x over previous
//
#include <hip/hip_runtime.h>

// ThetaGammaCLEVRN — hybrid R12 = R9 (W-in-LDS, swizzled gload_lds staging)
//                           + R11 (x via MFMA with k-permutation trick).
// Math reduction (phase network dead; theta amps == 1):
//   sf[16] = sum_o scene[e,o,:]
//   x[g]   = sf@(0.1*Ws) + bs           -> mfma_f32_16x16x16f16 (4 tiles)
//   ga[g]  = F20(sigmoid(x[g]))         -> 512-entry LUT
//   h      = relu(W @ act), W=[W1g|Weff|beff] (64x125), act=[ga;q;1]
//   out    = log_softmax(h @ W2 + b2)   -> mfma_f32_16x16x32_f16 (16)
// k-PERMUTATION: W's gamma columns permuted at prep so the x-MFMA D-layout
// lands exactly in this lane's H-MFMA B-frag slots (verified R11):
//   slot k=32c+8kb+i -> g=(2c+(i>>2))*16+4kb+(i&3).
// W A-frags from LDS (R11's global-W regressed: VGPR cap serialized loads).

typedef __fp16 h2_t  __attribute__((ext_vector_type(2)));
typedef __fp16 f16x4 __attribute__((ext_vector_type(4)));
typedef __fp16 f16x8 __attribute__((ext_vector_type(8)));
typedef float  f32x4 __attribute__((ext_vector_type(4)));
typedef unsigned u32x4 __attribute__((ext_vector_type(4)));

union H2U { unsigned u; h2_t h; };
union F4  { unsigned u[2]; f16x4 h; };
union F8  { u32x4 u; f16x8 h; };

__device__ __forceinline__ unsigned pk(float a, float b) {
    H2U v; v.h = __builtin_amdgcn_cvt_pkrtz(a, b);
    return v.u;
}
__device__ __forceinline__ float F20(float g) {
    #pragma unroll
    for (int n = 0; n < 20; ++n) {
        float g2 = g * g;
        g = fmaf(0.01f, g * (1.0f - g2), g);
    }
    return g;
}

// ws global layout (u32/f32 words):
//   0    : Wh   [64][64] fp16 pairs, row j, pair p -> k-slots (2p,2p+1);
//          gamma (p<32) k-PERMUTED per g(k); p in[32,62) Weff; p==62 beff|0
//   4096 : ws2T [8][64]  fp16 pairs (0.1*Ws[2dp][g], 0.1*Ws[2dp+1][g])
//   4608 : LUT  [512]x2  (F(x_i), F(x_{i+1})-F(x_i)), x_i = i/64 - 4
//   5632 : bs   [64] f32
//   5696 : w2   [128] f32 (W2 row-major)
//   5824 : b2   [2] f32 ; pad zeros to 5888
#define NWP 5888

__global__ void prep_kernel(const float* __restrict__ Ws,
                            const float* __restrict__ bs,
                            const float* __restrict__ Wq,
                            const float* __restrict__ bq,
                            const float* __restrict__ W1,
                            const float* __restrict__ b1,
                            const float* __restrict__ W2,
                            const float* __restrict__ b2,
                            float* __restrict__ ws) {
    __shared__ float W1q[64 * 64];            // W1 rows 80..143 (16 KB)
    const int t = threadIdx.x;
    #pragma unroll
    for (int i = 0; i < 16; ++i) {            // coalesced stage
        const int idx = t + (i << 8);
        W1q[idx] = W1[80 * 64 + idx];
    }
    __syncthreads();

    unsigned* wsu = (unsigned*)ws;
    int gid = blockIdx.x * 256 + t;
    if (gid < 4096) {                         // Wh pairs
        int j = gid >> 6, p = gid & 63;
        float va = 0.f, vb = 0.f;
        if (p < 32) {                         // gamma, k-permuted
            int c = p >> 4, kb = (p >> 2) & 3, i0 = (2 * p) & 7;
            int g0 = ((c << 1) + (i0 >> 2)) * 16 + (kb << 2) + (i0 & 3);
            va = W1[(16 + g0) * 64 + j];
            vb = W1[(17 + g0) * 64 + j];
        } else if (p < 62) {                  // Weff dims d0,d0+1 (identity)
            int d0 = 2 * p - 64;
            float s0 = 0.f, s1 = 0.f, s2 = 0.f, s3 = 0.f;
            #pragma unroll 8
            for (int c = 0; c < 64; c += 2) {
                float w0 = W1q[c * 64 + j];
                float w1 = W1q[(c + 1) * 64 + j];
                s0 = fmaf(Wq[d0 * 64 + c],           w0, s0);
                s1 = fmaf(Wq[(d0 + 1) * 64 + c],     w0, s1);
                s2 = fmaf(Wq[d0 * 64 + c + 1],       w1, s2);
                s3 = fmaf(Wq[(d0 + 1) * 64 + c + 1], w1, s3);
            }
            va = s0 + s2; vb = s1 + s3;
        } else if (p == 62) {                 // k=124: beff ; k=125: 0
            float acc = b1[j];
            #pragma unroll
            for (int r = 0; r < 16; ++r) acc += W1[r * 64 + j];
            #pragma unroll 16
            for (int c = 0; c < 64; ++c)
                acc = fmaf(bq[c], W1q[c * 64 + j], acc);
            va = acc; vb = 0.f;
        }
        wsu[gid] = pk(va, vb);
    } else if (gid < 4608) {                  // ws2T
        int w = gid - 4096, dp = w >> 6, g = w & 63;
        wsu[gid] = pk(0.1f * Ws[(2 * dp) * 64 + g],
                      0.1f * Ws[(2 * dp + 1) * 64 + g]);
    } else if (gid < 5632) {                  // LUT
        int li = gid - 4608, i = li >> 1;
        float x0 = (float)i * 0.015625f - 4.0f;
        float F0 = F20(1.0f / (1.0f + expf(-x0)));
        if (li & 1) {
            float F1 = F20(1.0f / (1.0f + expf(-(x0 + 0.015625f))));
            ws[gid] = F1 - F0;
        } else {
            ws[gid] = F0;
        }
    } else if (gid < 5696) {                  // bs
        ws[gid] = bs[gid - 5632];
    } else if (gid < 5824) {                  // W2 flat copy
        ws[gid] = W2[gid - 5696];
    } else if (gid < NWP) {
        ws[gid] = (gid == 5824) ? b2[0] : (gid == 5825) ? b2[1] : 0.f;
    }
}

// LDS: lds[NWP] mirrors ws layout (Wh source-swizzled); actS separate.
#define WS2o 4096
#define LUTo 4608
#define BSo  5632
#define W2o  5696
#define QP   72
#define ACTW 2816        // sfT[8][64] at 0, qT[32][72] at 512

__global__ __launch_bounds__(256, 4) void fused_kernel(
    const float* __restrict__ scene,   // (B,10,16)
    const float* __restrict__ query,   // (B,60)
    const float* __restrict__ wsbuf,   // NWP words
    float* __restrict__ out)           // (B,2)
{
    __shared__ unsigned lds[NWP];      // 23.0 KB constants
    __shared__ unsigned actS[ACTW];    // 11.3 KB activations

    const int t    = threadIdx.x;
    const int lane = t & 63;
    const int wv   = __builtin_amdgcn_readfirstlane(t) >> 6;   // SGPR wave id
    const int eb   = blockIdx.x << 6;      // 64 elements per block
    const unsigned* wsu = (const unsigned*)wsbuf;
    const float* ldsf = (const float*)lds;

    // ---- 1) async const staging: 23 chunks x 1 KB; Wh source-swizzled ----
    #pragma unroll
    for (int i = 0; i < 6; ++i) {
        const int chunk = wv * 6 + i;
        if (chunk < 23) {
            const int widx = (chunk << 8) | (lane << 2);
            const int src  = (widx < 4096) ? (widx ^ (((widx >> 6) & 7) << 2))
                                           : widx;
            __builtin_amdgcn_global_load_lds(
                (const __attribute__((address_space(1))) unsigned*)(wsu + src),
                (__attribute__((address_space(3))) unsigned*)&lds[chunk << 8],
                16, 0, 0);
        }
    }

    const int sel = t >> 2, q4 = t & 3;
    // ---- 2) scene: object-sum -> transposed fp16 pairs sfT[8][64] ----
    {
        const float4* sp = (const float4*)scene + (size_t)(eb + sel) * 40 + q4;
        float4 a = sp[0];
        #pragma unroll
        for (int o = 1; o < 10; ++o) {
            float4 v = sp[4 * o];
            a.x += v.x; a.y += v.y; a.z += v.z; a.w += v.w;
        }
        actS[((q4 << 1) + 0) * 64 + sel] = pk(a.x, a.y);
        actS[((q4 << 1) + 1) * 64 + sel] = pk(a.z, a.w);
    }
    // ---- 3) query -> transposed fp16 pairs qT[32][72] ----
    #pragma unroll
    for (int i = 0; i < 4; ++i) {
        const int idx = t + (i << 8);
        if (idx < 960) {
            const int qel = idx / 15, kq = idx - qel * 15;
            float4 qv = ((const float4*)query)[(size_t)(eb + qel) * 15 + kq];
            actS[512 + (2 * kq + 0) * QP + qel] = pk(qv.x, qv.y);
            actS[512 + (2 * kq + 1) * QP + qel] = pk(qv.z, qv.w);
        }
    }
    // ---- 4) pad rows: k=124 const-1 (beff), k=125..127 zero ----
    if (t < 64)       actS[512 + 30 * QP + t]        = pk(1.0f, 0.0f);
    else if (t < 128) actS[512 + 31 * QP + (t - 64)] = 0u;

    __syncthreads();   // consts + activations ready (drains gload_lds)

    // ============ compute: wave owns 16 elements (one MFMA N-tile) ========
    const int kb  = lane >> 4;
    const int q   = lane & 15;
    const int elb = ((t >> 6) << 4) | q;

    // ---- x-MFMAs: x[g][el] = bs[g] + sf @ (0.1*Ws), 4 tiles of 16 g ----
    F4 bsf;
    bsf.u[0] = actS[(2 * kb + 0) * 64 + elb];
    bsf.u[1] = actS[(2 * kb + 1) * 64 + elb];
    f32x4 xs[4];
    #pragma unroll
    for (int tt = 0; tt < 4; ++tt) {
        F4 aW;
        aW.u[0] = lds[WS2o + (2 * kb + 0) * 64 + tt * 16 + q];
        aW.u[1] = lds[WS2o + (2 * kb + 1) * 64 + tt * 16 + q];
        f32x4 cinit = *(const f32x4*)&ldsf[BSo + tt * 16 + (kb << 2)];
        xs[tt] = __builtin_amdgcn_mfma_f32_16x16x16f16(aW.h, bsf.h, cinit, 0, 0, 0);
    }

    // ---- LUT (sigmoid + 20-step Euler fused) + pack gamma B-frags ----
    auto GA = [&](float x) -> float {
        float u = fminf(fmaxf(fmaf(x, 64.0f, 256.0f), 0.0f), 511.0f);
        int   i0 = (int)u;
        float2 e = *(const float2*)&ldsf[LUTo + (i0 << 1)];
        return fmaf(u - (float)i0, e.y, e.x);
    };
    F8 bfrag[4];
    #pragma unroll
    for (int c = 0; c < 2; ++c) {
        F8 f;
        f.u[0] = pk(GA(xs[2 * c][0]),     GA(xs[2 * c][1]));
        f.u[1] = pk(GA(xs[2 * c][2]),     GA(xs[2 * c][3]));
        f.u[2] = pk(GA(xs[2 * c + 1][0]), GA(xs[2 * c + 1][1]));
        f.u[3] = pk(GA(xs[2 * c + 1][2]), GA(xs[2 * c + 1][3]));
        bfrag[c] = f;
    }
    // ---- query B-frags c=2,3 (includes const-1 beff column) ----
    #pragma unroll
    for (int c2 = 0; c2 < 2; ++c2) {
        F8 f;
        #pragma unroll
        for (int r = 0; r < 4; ++r)
            f.u[r] = actS[512 + ((kb << 2) + r + (c2 << 4)) * QP + elb];
        bfrag[2 + c2] = f;
    }

    // ---- H-MFMA: 4 j-tiles x 4 k-chunks; W A-frags from swizzled LDS ----
    float l0 = 0.f, l1 = 0.f;
    #pragma unroll
    for (int jt = 0; jt < 4; ++jt) {
        f32x4 acc = {0.f, 0.f, 0.f, 0.f};
        const int j = (jt << 4) | q;
        #pragma unroll
        for (int c = 0; c < 4; ++c) {
            const int ch = ((c << 2) | kb) ^ (j & 7);
            F8 a;
            a.u = *(const u32x4*)&lds[(j << 6) + (ch << 2)];
            acc = __builtin_amdgcn_mfma_f32_16x16x32_f16(a.h, bfrag[c].h, acc, 0, 0, 0);
        }
        #pragma unroll
        for (int r = 0; r < 4; ++r) {
            const int jr = (jt << 4) + (kb << 2) + r;
            float hv = fmaxf(acc[r], 0.f);
            float2 wv2 = *(const float2*)&ldsf[W2o + (jr << 1)];
            l0 = fmaf(hv, wv2.x, l0);
            l1 = fmaf(hv, wv2.y, l1);
        }
    }
    // ---- reduce over k-groups, log_softmax, store ----
    l0 += __shfl_xor(l0, 16); l0 += __shfl_xor(l0, 32);
    l1 += __shfl_xor(l1, 16); l1 += __shfl_xor(l1, 32);
    l0 += wsbuf[5824]; l1 += wsbuf[5825];
    if (lane < 16) {
        const float mx = fmaxf(l0, l1);
        const float lz = mx + __logf(__expf(l0 - mx) + __expf(l1 - mx));
        float2 o = { l0 - lz, l1 - lz };
        ((float2*)out)[eb + elb] = o;
    }
}

extern "C" void kernel_launch(void* const* d_in, const int* in_sizes, int n_in,
                              void* d_out, int out_size, void* d_ws, size_t ws_size,
                              hipStream_t stream) {
    const float* scene = (const float*)d_in[0];
    const float* query = (const float*)d_in[1];
    // d_in[2..5] = theta/gamma phase & freq: provably unused by the output
    const float* Ws = (const float*)d_in[6];
    const float* bs = (const float*)d_in[7];
    const float* Wq = (const float*)d_in[8];
    const float* bq = (const float*)d_in[9];
    const float* W1 = (const float*)d_in[10];
    const float* b1 = (const float*)d_in[11];
    const float* W2 = (const float*)d_in[12];
    const float* b2 = (const float*)d_in[13];
    float* out = (float*)d_out;
    float* ws  = (float*)d_ws;   // needs NWP*4 = 23.6 KB

    const int B = in_sizes[0] / 160;   // 65536
    prep_kernel<<<23, 256, 0, stream>>>(Ws, bs, Wq, bq, W1, b1, W2, b2, ws);
    fused_kernel<<<B / 64, 256, 0, stream>>>(scene, query, ws, out);
}

// Round 13
// 22.234 us; speedup vs baseline: 1.3043x; 1.0495x over previous
//
#include <hip/hip_runtime.h>

// ThetaGammaCLEVRN — single-kernel all-MFMA (R13). No prep kernel.
// Math (phase network dead; theta amps == 1):
//   sf = sum_o scene[e,o,:];  x = sf@(0.1*Ws)+bs  -> mfma 16x16x16 (4)
//   ga = F20(sigmoid(x)) via 257-entry LUT (computed in-block)
//   Weff[d][j] = sum_c Wq[d][c]*W1[80+c][j]       -> mfma 16x16x32 (32/wave)
//   h = relu([W1g|Weff']@[ga;q';1]), logits=h@W2+b2, out=log_softmax
// PERMUTATION TRICK (verified R11/R12): D-layout row=16T+4kb+reg, col=lane&15.
// Gamma k-slots: slot(c,kb,i) -> g=(2c+(i>>2))*16+4kb+(i&3)  (W1g rows
// permuted at stage). Query k-slots: same map on d -> Weff-MFMA D packs
// DIRECTLY into H-MFMA A-frags; qT pair-rows permuted to match:
// float4 a -> rows p0(a), p0+1 with p0 = 16(a>>3)+4(a&3)+2((a>>2)&1).
// bq = Wq row 60 (act slot d'=60 holds 1.0 = qT row 30, same as before);
// b1 + sum_{r<16}W1[r] enters as C-init of the dt=3 Weff-MFMA (kb==3,reg0).

typedef __fp16 h2_t  __attribute__((ext_vector_type(2)));
typedef __fp16 f16x4 __attribute__((ext_vector_type(4)));
typedef __fp16 f16x8 __attribute__((ext_vector_type(8)));
typedef float  f32x4 __attribute__((ext_vector_type(4)));
typedef unsigned u32x4 __attribute__((ext_vector_type(4)));

union H2U { unsigned u; h2_t h; };
union F4  { unsigned u[2]; f16x4 h; };
union F8  { u32x4 u; f16x8 h; };

__device__ __forceinline__ unsigned pk(float a, float b) {
    H2U v; v.h = __builtin_amdgcn_cvt_pkrtz(a, b);
    return v.u;
}
__device__ __forceinline__ float F20(float g) {
    #pragma unroll
    for (int n = 0; n < 20; ++n) {
        float g2 = g * g;
        g = fmaf(0.01f, g * (1.0f - g2), g);
    }
    return g;
}

// LDS word offsets
#define WHo   0                    // gamma Wh [64 j][32 pairs] u32, swizzled
#define WQTo  2048                 // W1qT [32 cpair][65] u32
#define WS2o  4128                 // ws2T [8][64] u32
#define LUTo  4640                 // 257 f32 (+3 pad)
#define BSo   4900                 // bs 64 f32
#define BSUMo 4964                 // b1+sum W1[0:16] 64 f32
#define W2o   5028                 // W2 128 f32
#define SFTo  5156                 // sfT [8][64] u32
#define QTo   5668                 // qT [32][66] u32 (permuted rows)
#define LDSW  (QTo + 32 * 66)      // 7780 words = 30.4 KB

__global__ __launch_bounds__(256, 4) void fused_kernel(
    const float* __restrict__ scene,   // (B,10,16)
    const float* __restrict__ query,   // (B,60)
    const float* __restrict__ Ws,      // (16,64)
    const float* __restrict__ bs,      // (64)
    const float* __restrict__ Wq,      // (60,64)
    const float* __restrict__ bq,      // (64)
    const float* __restrict__ W1,      // (144,64)
    const float* __restrict__ b1,      // (64)
    const float* __restrict__ W2,      // (64,2)
    const float* __restrict__ b2,      // (2)
    float* __restrict__ out)           // (B,2)
{
    __shared__ __align__(16) unsigned lds[LDSW];
    float* ldsF = (float*)lds;
    const int t    = threadIdx.x;
    const int lane = t & 63;
    const int wv   = __builtin_amdgcn_readfirstlane(t) >> 6;   // SGPR wave id
    const int kb   = lane >> 4;
    const int jw   = lane & 15;
    const int eb   = blockIdx.x << 6;      // 64 elements per block

    // ---- Wq A-frags (registers, per-lane): A[d][c], d=16dt+jw, c=32kk+8kb+i
    F8 aWq[4][2];
    #pragma unroll
    for (int dt = 0; dt < 4; ++dt) {
        const int d = (dt << 4) + jw;
        #pragma unroll
        for (int kk = 0; kk < 2; ++kk) {
            const int c0 = (kk << 5) + (kb << 3);
            float4 lo = {0.f,0.f,0.f,0.f}, hi = {0.f,0.f,0.f,0.f};
            if (d < 60) {
                lo = *(const float4*)(Wq + d * 64 + c0);
                hi = *(const float4*)(Wq + d * 64 + c0 + 4);
            } else if (d == 60) {          // bq rides as Wq row 60
                lo = *(const float4*)(bq + c0);
                hi = *(const float4*)(bq + c0 + 4);
            }
            F8 f;
            f.u[0] = pk(lo.x, lo.y); f.u[1] = pk(lo.z, lo.w);
            f.u[2] = pk(hi.x, hi.y); f.u[3] = pk(hi.z, hi.w);
            aWq[dt][kk] = f;
        }
    }

    // ---- stage gamma Wh: j=lane, chunks 2wv,2wv+1 (g-permuted pair rows) --
    {
        const int j = lane;
        #pragma unroll
        for (int ii = 0; ii < 2; ++ii) {
            const int ch = (wv << 1) + ii;
            u32x4 v;
            #pragma unroll
            for (int pp = 0; pp < 4; ++pp) {
                const int p  = (ch << 2) + pp;
                const int g0 = (((p >> 4) << 1) + ((p & 3) >> 1)) * 16
                             + (((p >> 2) & 3) << 2) + ((p & 1) << 1);
                v[pp] = pk(W1[(16 + g0) * 64 + j], W1[(17 + g0) * 64 + j]);
            }
            *(u32x4*)&lds[WHo + (j << 5) + ((ch ^ (j & 7)) << 2)] = v;
        }
        // ---- stage W1qT: cpair rows 8wv..8wv+7, col j ----
        #pragma unroll
        for (int ii = 0; ii < 8; ++ii) {
            const int cp = (wv << 3) + ii;
            lds[WQTo + cp * 65 + j] =
                pk(W1[(80 + 2 * cp) * 64 + j], W1[(81 + 2 * cp) * 64 + j]);
        }
    }
    // ---- stage ws2T [dp][g] ----
    #pragma unroll
    for (int ii = 0; ii < 2; ++ii) {
        const int w = t + (ii << 8);
        const int dp = w >> 6, g = w & 63;
        lds[WS2o + w] = pk(0.1f * Ws[(2 * dp) * 64 + g],
                           0.1f * Ws[(2 * dp + 1) * 64 + g]);
    }
    // ---- LUT: F20(sigmoid(x)), x = i/32 - 4, 257 entries ----
    {
        float x0 = (float)t * 0.03125f - 4.0f;
        ldsF[LUTo + t] = F20(1.0f / (1.0f + __expf(-x0)));
        if (t == 0) ldsF[LUTo + 256] = F20(1.0f / (1.0f + __expf(-4.0f)));
    }
    // ---- bsum / bs / w2 ----
    if (t < 64) {
        float s = b1[t];
        #pragma unroll
        for (int r = 0; r < 16; ++r) s += W1[r * 64 + t];
        ldsF[BSUMo + t] = s;
    } else if (t < 128) {
        ldsF[BSo + (t - 64)] = bs[t - 64];
    } else {
        ldsF[W2o + (t - 128)] = W2[t - 128];
    }
    // ---- scene: object-sum -> sfT[8][64] ----
    const int sel = t >> 2, q4 = t & 3;
    {
        const float4* sp = (const float4*)scene + (size_t)(eb + sel) * 40 + q4;
        float4 a = sp[0];
        #pragma unroll
        for (int o = 1; o < 10; ++o) {
            float4 v = sp[4 * o];
            a.x += v.x; a.y += v.y; a.z += v.z; a.w += v.w;
        }
        lds[SFTo + ((q4 << 1) + 0) * 64 + sel] = pk(a.x, a.y);
        lds[SFTo + ((q4 << 1) + 1) * 64 + sel] = pk(a.z, a.w);
    }
    // ---- query -> qT[32][66], PERMUTED pair rows ----
    #pragma unroll
    for (int i = 0; i < 4; ++i) {
        const int idx = t + (i << 8);
        if (idx < 960) {
            const int qel = idx / 15, aq = idx - qel * 15;
            float4 qv = ((const float4*)query)[(size_t)(eb + qel) * 15 + aq];
            const int p0 = ((aq >> 3) << 4) + ((aq & 3) << 2) + (((aq >> 2) & 1) << 1);
            lds[QTo + (p0 + 0) * 66 + qel] = pk(qv.x, qv.y);
            lds[QTo + (p0 + 1) * 66 + qel] = pk(qv.z, qv.w);
        }
    }
    if (t < 64)       lds[QTo + 30 * 66 + t]        = pk(1.0f, 0.0f);  // d'=60
    else if (t < 128) lds[QTo + 31 * 66 + (t - 64)] = 0u;              // d'=62,63
    __syncthreads();

    // ============ compute: wave owns 16 elements ============
    const int q   = jw;
    const int elb = ((t >> 6) << 4) | q;

    // ---- x-MFMAs ----
    F4 bsf;
    bsf.u[0] = lds[SFTo + (2 * kb + 0) * 64 + elb];
    bsf.u[1] = lds[SFTo + (2 * kb + 1) * 64 + elb];
    f32x4 xs[4];
    #pragma unroll
    for (int tt = 0; tt < 4; ++tt) {
        F4 aW;
        aW.u[0] = lds[WS2o + (2 * kb + 0) * 64 + tt * 16 + q];
        aW.u[1] = lds[WS2o + (2 * kb + 1) * 64 + tt * 16 + q];
        f32x4 cinit = *(const f32x4*)&ldsF[BSo + tt * 16 + (kb << 2)];
        xs[tt] = __builtin_amdgcn_mfma_f32_16x16x16f16(aW.h, bsf.h, cinit, 0, 0, 0);
    }
    // ---- LUT eval + gamma B-frags ----
    auto GA = [&](float x) -> float {
        float u = fminf(fmaxf(fmaf(x, 32.0f, 128.0f), 0.0f), 255.999f);
        int   i0 = (int)u;
        float f0 = ldsF[LUTo + i0], f1 = ldsF[LUTo + i0 + 1];
        return fmaf(u - (float)i0, f1 - f0, f0);
    };
    F8 bfrag[4];
    #pragma unroll
    for (int c = 0; c < 2; ++c) {
        F8 f;
        f.u[0] = pk(GA(xs[2 * c][0]),     GA(xs[2 * c][1]));
        f.u[1] = pk(GA(xs[2 * c][2]),     GA(xs[2 * c][3]));
        f.u[2] = pk(GA(xs[2 * c + 1][0]), GA(xs[2 * c + 1][1]));
        f.u[3] = pk(GA(xs[2 * c + 1][2]), GA(xs[2 * c + 1][3]));
        bfrag[c] = f;
    }
    #pragma unroll
    for (int c2 = 0; c2 < 2; ++c2) {
        F8 f;
        #pragma unroll
        for (int r = 0; r < 4; ++r)
            f.u[r] = lds[QTo + ((kb << 2) + r + (c2 << 4)) * 66 + elb];
        bfrag[2 + c2] = f;
    }

    // ---- per j-tile: Weff via MFMA -> qA frags -> H-MFMA -> epilogue ----
    float l0 = 0.f, l1 = 0.f;
    #pragma unroll
    for (int jt = 0; jt < 4; ++jt) {
        const int j = (jt << 4) | q;
        F8 Bk[2];
        #pragma unroll
        for (int kk = 0; kk < 2; ++kk) {
            F8 f;
            #pragma unroll
            for (int r = 0; r < 4; ++r)
                f.u[r] = lds[WQTo + ((kk << 4) + (kb << 2) + r) * 65 + j];
            Bk[kk] = f;
        }
        const float bsv = ldsF[BSUMo + j];
        F8 qA[2];
        #pragma unroll
        for (int half = 0; half < 2; ++half) {
            f32x4 accT[2];
            #pragma unroll
            for (int dd = 0; dd < 2; ++dd) {
                const int dt = (half << 1) + dd;
                f32x4 c0 = {0.f, 0.f, 0.f, 0.f};
                if (dt == 3) c0[0] = (kb == 3) ? bsv : 0.f;   // d==60 row
                f32x4 a1 = __builtin_amdgcn_mfma_f32_16x16x32_f16(
                               aWq[dt][0].h, Bk[0].h, c0, 0, 0, 0);
                accT[dd] = __builtin_amdgcn_mfma_f32_16x16x32_f16(
                               aWq[dt][1].h, Bk[1].h, a1, 0, 0, 0);
            }
            F8 f;
            f.u[0] = pk(accT[0][0], accT[0][1]);
            f.u[1] = pk(accT[0][2], accT[0][3]);
            f.u[2] = pk(accT[1][0], accT[1][1]);
            f.u[3] = pk(accT[1][2], accT[1][3]);
            qA[half] = f;
        }
        f32x4 hacc = {0.f, 0.f, 0.f, 0.f};
        #pragma unroll
        for (int c = 0; c < 2; ++c) {
            const int ch = ((c << 2) | kb) ^ (j & 7);
            F8 a;
            a.u = *(const u32x4*)&lds[WHo + (j << 5) + (ch << 2)];
            hacc = __builtin_amdgcn_mfma_f32_16x16x32_f16(a.h, bfrag[c].h, hacc, 0, 0, 0);
        }
        hacc = __builtin_amdgcn_mfma_f32_16x16x32_f16(qA[0].h, bfrag[2].h, hacc, 0, 0, 0);
        hacc = __builtin_amdgcn_mfma_f32_16x16x32_f16(qA[1].h, bfrag[3].h, hacc, 0, 0, 0);
        #pragma unroll
        for (int r = 0; r < 4; ++r) {
            const int jr = (jt << 4) + (kb << 2) + r;
            float hv = fmaxf(hacc[r], 0.f);
            float2 wv2 = *(const float2*)&ldsF[W2o + (jr << 1)];
            l0 = fmaf(hv, wv2.x, l0);
            l1 = fmaf(hv, wv2.y, l1);
        }
    }
    // ---- reduce over k-groups, log_softmax, store ----
    l0 += __shfl_xor(l0, 16); l0 += __shfl_xor(l0, 32);
    l1 += __shfl_xor(l1, 16); l1 += __shfl_xor(l1, 32);
    l0 += b2[0]; l1 += b2[1];
    if (lane < 16) {
        const float mx = fmaxf(l0, l1);
        const float lz = mx + __logf(__expf(l0 - mx) + __expf(l1 - mx));
        float2 o = { l0 - lz, l1 - lz };
        ((float2*)out)[eb + elb] = o;
    }
}

extern "C" void kernel_launch(void* const* d_in, const int* in_sizes, int n_in,
                              void* d_out, int out_size, void* d_ws, size_t ws_size,
                              hipStream_t stream) {
    const float* scene = (const float*)d_in[0];
    const float* query = (const float*)d_in[1];
    // d_in[2..5] = theta/gamma phase & freq: provably unused by the output
    const float* Ws = (const float*)d_in[6];
    const float* bs = (const float*)d_in[7];
    const float* Wq = (const float*)d_in[8];
    const float* bq = (const float*)d_in[9];
    const float* W1 = (const float*)d_in[10];
    const float* b1 = (const float*)d_in[11];
    const float* W2 = (const float*)d_in[12];
    const float* b2 = (const float*)d_in[13];
    float* out = (float*)d_out;

    const int B = in_sizes[0] / 160;   // 65536
    fused_kernel<<<B / 64, 256, 0, stream>>>(scene, query, Ws, bs, Wq, bq,
                                             W1, b1, W2, b2, out);
}